// Round 1
// baseline (1158.695 us; speedup 1.0000x reference)
//
#include <hip/hip_runtime.h>

#define Bz   8
#define Hh   32
#define Wd   32
#define CIN  64
#define COUT 64
#define NOUT 32
#define NFLAT (Hh*Wd*COUT)   // 65536
#define NIN   (Hh*Wd*CIN)    // 65536

// Pre-kernel: transpose kernel [3][3][CIN][COUT] -> kt[tap][COUT][CIN]
__global__ void k_transpose(const float* __restrict__ k, float* __restrict__ kt) {
    int idx = blockIdx.x * 256 + threadIdx.x;       // 9*64*64 = 36864
    if (idx >= 9 * CIN * COUT) return;
    int co  = idx & 63;
    int ci  = (idx >> 6) & 63;
    int tap = idx >> 12;
    kt[(tap * COUT + co) * CIN + ci] = k[idx];
}

// Init bias outputs with b_out_u / b_out_l (conv kernel atomicAdds partials on top)
__global__ void k_init_bias(const float* __restrict__ buI, const float* __restrict__ blI,
                            float* __restrict__ buO, float* __restrict__ blO) {
    int i = threadIdx.x;                            // 256 threads, 1 block
    buO[i] = buI[i];
    blO[i] = blI[i];
}

__global__ __launch_bounds__(256) void k_convt(
    const float* __restrict__ wu, const float* __restrict__ wl,
    const float* __restrict__ kt, const float* __restrict__ bias,
    float* __restrict__ outU, float* __restrict__ outL,
    float* __restrict__ buO, float* __restrict__ blO)
{
    __shared__ float bias_lds[COUT];
    int t = threadIdx.x;
    if (t < COUT) bias_lds[t] = bias[t];
    __syncthreads();

    int bid = blockIdx.x;            // 8 * 32 * 8 = 2048 blocks
    int wg  = bid & 7;               // 8 w-groups of 4
    int h   = (bid >> 3) & 31;
    int b   = bid >> 8;

    int o   = t & 31;                // lane-within-32: n_out index (stride-1 in memory)
    int g   = t >> 5;                // 8 ci-groups
    int ci0 = g << 3;
    int w0  = wg << 2;

    float accU[4][8], accL[4][8];
    #pragma unroll
    for (int p = 0; p < 4; p++)
        #pragma unroll
        for (int i = 0; i < 8; i++) { accU[p][i] = 0.f; accL[p][i] = 0.f; }

    float bu_part = 0.f, bl_part = 0.f;

    #pragma unroll
    for (int kh = 0; kh < 3; kh++) {
        int hh = h + 1 - kh;                       // adjoint: ct[h+1-kh, w+1-kw]
        if ((unsigned)hh >= Hh) continue;
        #pragma unroll
        for (int kw = 0; kw < 3; kw++) {
            const int tap = kh * 3 + kw;
            const float* ktp = kt + tap * (COUT * CIN) + ci0;
            int wbase = w0 + 1 - kw;
            int rowb  = (b * NFLAT + hh * (Wd * COUT)) * NOUT + o;

            for (int co = 0; co < COUT; co++) {
                float4 k0 = *(const float4*)(ktp + co * CIN);
                float4 k1 = *(const float4*)(ktp + co * CIN + 4);
                float kk[8] = {k0.x, k0.y, k0.z, k0.w, k1.x, k1.y, k1.z, k1.w};
                #pragma unroll
                for (int p = 0; p < 4; p++) {
                    int ww = wbase + p;
                    if ((unsigned)ww >= Wd) continue;   // block-uniform branch
                    int idx = rowb + (ww * COUT + co) * NOUT;
                    float uv = wu[idx];
                    float lv = wl[idx];
                    #pragma unroll
                    for (int i = 0; i < 8; i++) {
                        accU[p][i] = fmaf(uv, kk[i], accU[p][i]);
                        accL[p][i] = fmaf(lv, kk[i], accL[p][i]);
                    }
                    if (tap == 4 && g == 0) {           // center tap visits every wu elem once
                        bu_part = fmaf(uv, bias_lds[co], bu_part);
                        bl_part = fmaf(lv, bias_lds[co], bl_part);
                    }
                }
            }
        }
    }

    // coalesced stores: o is stride-1
    #pragma unroll
    for (int p = 0; p < 4; p++) {
        int w  = w0 + p;
        int ob = (b * NIN + (h * Wd + w) * CIN + ci0) * NOUT + o;
        #pragma unroll
        for (int i = 0; i < 8; i++) {
            outU[ob + i * NOUT] = accU[p][i];
            outL[ob + i * NOUT] = accL[p][i];
        }
    }

    if (g == 0) {
        atomicAdd(&buO[b * NOUT + o], bu_part);
        atomicAdd(&blO[b * NOUT + o], bl_part);
    }
}

extern "C" void kernel_launch(void* const* d_in, const int* in_sizes, int n_in,
                              void* d_out, int out_size, void* d_ws, size_t ws_size,
                              hipStream_t stream) {
    // inputs: x (unused), w_out_u, b_out_u, w_out_l, b_out_l, kernel, bias
    const float* wu   = (const float*)d_in[1];
    const float* buI  = (const float*)d_in[2];
    const float* wl   = (const float*)d_in[3];
    const float* blI  = (const float*)d_in[4];
    const float* kk   = (const float*)d_in[5];
    const float* bias = (const float*)d_in[6];

    float* out  = (float*)d_out;
    float* outU = out;                                // [8,1,65536,32]
    float* buO  = out + 16777216;                     // [8,1,32]
    float* outL = out + 16777216 + 256;               // [8,1,65536,32]
    float* blO  = out + 2 * 16777216 + 256;           // [8,1,32]

    float* kt = (float*)d_ws;                         // 147456 B

    k_transpose<<<144, 256, 0, stream>>>(kk, kt);
    k_init_bias<<<1, 256, 0, stream>>>(buI, blI, buO, blO);
    k_convt<<<2048, 256, 0, stream>>>(wu, wl, kt, bias, outU, outL, buO, blO);
}

// Round 2
// 151.811 us; speedup vs baseline: 7.6325x; 7.6325x over previous
//
#include <hip/hip_runtime.h>
#include <cstdint>

#define NOUT 32

typedef __attribute__((ext_vector_type(8))) short short8;
typedef __attribute__((ext_vector_type(16))) float f32x16;

__device__ inline uint16_t f2bf(float f) {
    union { float f; uint32_t u; } x; x.f = f;
    uint32_t r = (x.u + 0x7FFF + ((x.u >> 16) & 1)) >> 16;
    return (uint16_t)r;
}

// Convert kernel fp32 [9][64][64] -> bf16 ktb (same order), init bias outputs.
__global__ void k_prep(const float* __restrict__ kk, uint16_t* __restrict__ ktb,
                       const float* __restrict__ buI, const float* __restrict__ blI,
                       float* __restrict__ buO, float* __restrict__ blO) {
    int i = blockIdx.x * 256 + threadIdx.x;
    if (i < 36864) ktb[i] = f2bf(kk[i]);
    else if (i < 36864 + 256) buO[i - 36864] = buI[i - 36864];
    else if (i < 36864 + 512) blO[i - 36864 - 256] = blI[i - 36864 - 256];
}

// Block: (b, UL, h, w-chunk of 8). 256 threads = 4 waves, wave owns 2 w's.
// LDS: 3 rows x 10 sites, each site = [32 o][64 co] bf16, XOR-swizzled 16B chunks.
__global__ __launch_bounds__(256) void k_main(
    const float* __restrict__ wu, const float* __restrict__ wl,
    const uint16_t* __restrict__ ktb, const float* __restrict__ bias,
    float* __restrict__ outU, float* __restrict__ outL,
    float* __restrict__ buO, float* __restrict__ blO)
{
    __shared__ uint16_t tiles[30][2048];   // 122880 B
    __shared__ float bias_lds[64];
    __shared__ float bsum[NOUT];

    int t = threadIdx.x;
    int l = t & 63;             // lane
    int wv = t >> 6;            // wave 0..3
    int o  = l & 31;            // n_out index
    int ch = l >> 5;            // co-half within 16-chunk

    if (t < 64) bias_lds[t] = bias[t];
    if (t < NOUT) bsum[t] = 0.f;

    // decode with XCD-chunk swizzle: 2048 blocks, 8 XCDs, 256 per XCD,
    // h innermost so h-adjacent blocks land in the same XCD's L2.
    int bid  = blockIdx.x;
    int virt = (bid & 7) * 256 + (bid >> 3);
    int h    = virt & 31;
    int wc   = (virt >> 5) & 3;
    int UL   = (virt >> 7) & 1;
    int b    = virt >> 8;
    int w0   = wc * 8;

    const float* src = UL ? wl : wu;
    float* dst  = UL ? outL : outU;
    float* bdst = UL ? blO : buO;

    __syncthreads();   // bias_lds ready

    // ---- stage all 3 rows (kh = 0..2 -> hh = h+1-kh), 10 sites each ----
    float bp = 0.f;    // bias partial (this thread's o)
    for (int s = wv; s < 30; s += 4) {
        int r    = s / 10;
        int site = s - r * 10;
        int hh   = h + 1 - r;
        if ((unsigned)hh >= 32u) continue;          // row never read
        int ww = w0 - 1 + site;
        if ((unsigned)ww >= 32u) {
            short8 z = (short8)0;
            #pragma unroll
            for (int j = 0; j < 4; j++) {
                int chunk = 2 * j + ch;
                int off = o * 64 + ((chunk ^ (o & 7)) << 3);
                *(short8*)&tiles[s][off] = z;
            }
            continue;
        }
        const float* base = src + ((size_t)b * 65536 + (size_t)(hh * 32 + ww) * 64) * 32;
        #pragma unroll
        for (int j = 0; j < 4; j++) {
            int co0 = j * 16 + ch * 8;
            float g[8];
            #pragma unroll
            for (int e = 0; e < 8; e++) g[e] = base[(co0 + e) * 32 + o];
            if (r == 1 && site >= 1 && site <= 8) {
                #pragma unroll
                for (int e = 0; e < 8; e++) bp = fmaf(g[e], bias_lds[co0 + e], bp);
            }
            short8 v;
            #pragma unroll
            for (int e = 0; e < 8; e++) v[e] = (short)f2bf(g[e]);
            int chunk = 2 * j + ch;
            int off = o * 64 + ((chunk ^ (o & 7)) << 3);
            *(short8*)&tiles[s][off] = v;
        }
    }
    atomicAdd(&bsum[o], bp);
    __syncthreads();
    if (t < NOUT) atomicAdd(&bdst[b * NOUT + t], bsum[t]);

    // ---- MFMA phase ----
    f32x16 acc[2][2];   // [t = owned w 0/1][c = ci-tile 0/1]
    #pragma unroll
    for (int a = 0; a < 2; a++)
        #pragma unroll
        for (int c = 0; c < 2; c++) acc[a][c] = (f32x16)0.f;

    int wa = w0 + 2 * wv;          // wave's first owned w

    for (int r = 0; r < 3; r++) {
        int hh = h + 1 - r;
        if ((unsigned)hh >= 32u) continue;

        // A-frags: kernel[tap=r*3+kw][ci][co], lane: ci = c*32+(l&31), co = k*16+ch*8.. +e
        short8 Af[3][2][4];
        #pragma unroll
        for (int kw = 0; kw < 3; kw++)
            #pragma unroll
            for (int c = 0; c < 2; c++)
                #pragma unroll
                for (int k = 0; k < 4; k++) {
                    int ci = c * 32 + (l & 31);
                    int co = k * 16 + ch * 8;
                    Af[kw][c][k] = *(const short8*)&ktb[(((r * 3 + kw) * 64) + ci) * 64 + co];
                }

        #pragma unroll
        for (int wwl = 0; wwl < 4; wwl++) {
            int s = r * 10 + 2 * wv + wwl;
            short8 Bf[4];
            #pragma unroll
            for (int k = 0; k < 4; k++) {
                int chunk = k * 2 + ch;
                int off = o * 64 + ((chunk ^ (o & 7)) << 3);
                Bf[k] = *(const short8*)&tiles[s][off];
            }
            #pragma unroll
            for (int tw = 0; tw < 2; tw++) {
                int kw = tw + 2 - wwl;           // compile-time under unroll
                if (kw >= 0 && kw <= 2) {
                    #pragma unroll
                    for (int c = 0; c < 2; c++)
                        #pragma unroll
                        for (int k = 0; k < 4; k++)
                            acc[tw][c] = __builtin_amdgcn_mfma_f32_32x32x16_bf16(
                                Af[kw][c][k], Bf[k], acc[tw][c], 0, 0, 0);
                }
            }
        }
    }

    // ---- stores: D col = lane&31 = o (coalesced), row = (reg&3)+8*(reg>>2)+4*(lane>>5) ----
    #pragma unroll
    for (int tw = 0; tw < 2; tw++) {
        int w = wa + tw;
        #pragma unroll
        for (int c = 0; c < 2; c++) {
            float* base = dst + ((size_t)b * 65536 + (size_t)(h * 32 + w) * 64 + c * 32) * 32;
            #pragma unroll
            for (int reg = 0; reg < 16; reg++) {
                int row = (reg & 3) + 8 * (reg >> 2) + 4 * (l >> 5);
                base[row * 32 + o] = acc[tw][c][reg];
            }
        }
    }
}

extern "C" void kernel_launch(void* const* d_in, const int* in_sizes, int n_in,
                              void* d_out, int out_size, void* d_ws, size_t ws_size,
                              hipStream_t stream) {
    const float* wu   = (const float*)d_in[1];
    const float* buI  = (const float*)d_in[2];
    const float* wl   = (const float*)d_in[3];
    const float* blI  = (const float*)d_in[4];
    const float* kk   = (const float*)d_in[5];
    const float* bias = (const float*)d_in[6];

    float* out  = (float*)d_out;
    float* outU = out;
    float* buO  = out + 16777216;
    float* outL = out + 16777216 + 256;
    float* blO  = out + 2 * 16777216 + 256;

    uint16_t* ktb = (uint16_t*)d_ws;   // 73728 B

    k_prep<<<146, 256, 0, stream>>>(kk, ktb, buI, blI, buO, blO);
    k_main<<<2048, 256, 0, stream>>>(wu, wl, ktb, bias, outU, outL, buO, blO);
}

// Round 4
// 130.969 us; speedup vs baseline: 8.8471x; 1.1591x over previous
//
#include <hip/hip_runtime.h>
#include <cstdint>

typedef __attribute__((ext_vector_type(8))) short short8;
typedef __attribute__((ext_vector_type(16))) float f32x16;

__device__ inline uint16_t f2bf(float f) {
    union { float f; uint32_t u; } x; x.f = f;
    uint32_t r = (x.u + 0x7FFF + ((x.u >> 16) & 1)) >> 16;
    return (uint16_t)r;
}

// Convert kernel fp32 [9][64][64] -> bf16 ktb (same order), init bias outputs.
__global__ void k_prep(const float* __restrict__ kk, uint16_t* __restrict__ ktb,
                       const float* __restrict__ buI, const float* __restrict__ blI,
                       float* __restrict__ buO, float* __restrict__ blO) {
    int i = blockIdx.x * 256 + threadIdx.x;
    if (i < 36864) ktb[i] = f2bf(kk[i]);
    else if (i < 36864 + 256) buO[i - 36864] = buI[i - 36864];
    else if (i < 36864 + 512) blO[i - 36864 - 256] = blI[i - 36864 - 256];
}

// Block: (b, UL, h, w-chunk of 8). 4 waves, wave owns 2 w's.
// LDS: ONE kh-row of 10 sites, site = [32 o][64 co] bf16 XOR-swizzled 16B chunks.
// 10 * 4096 = 40960 B exactly -> 4 blocks/CU.
__global__ __launch_bounds__(256, 4) void k_main(
    const float* __restrict__ wu, const float* __restrict__ wl,
    const uint16_t* __restrict__ ktb, const float* __restrict__ bias,
    float* __restrict__ outU, float* __restrict__ outL,
    float* __restrict__ buO, float* __restrict__ blO)
{
    __shared__ uint16_t tiles[10][2048];    // 40960 B exactly

    int t  = threadIdx.x;
    int l  = t & 63;
    int wv = t >> 6;
    int o  = l & 31;            // n_out index (frag col, stride-1 in memory)
    int ch = l >> 5;            // co-half selector

    // XCD-chunk swizzle: h innermost within an XCD's contiguous chunk
    int bid  = blockIdx.x;
    int virt = (bid & 7) * 256 + (bid >> 3);
    int h    = virt & 31;
    int wc   = (virt >> 5) & 3;
    int UL   = (virt >> 7) & 1;
    int b    = virt >> 8;
    int w0   = wc * 8;

    const float* src = UL ? wl : wu;
    float* dst  = UL ? outL : outU;
    float* bdst = UL ? blO : buO;

    float bp = 0.f;             // bias partial for this thread's o

    f32x16 acc[2][2];
    #pragma unroll
    for (int a = 0; a < 2; a++)
        #pragma unroll
        for (int c = 0; c < 2; c++) acc[a][c] = (f32x16)0.f;

    for (int r = 0; r < 3; r++) {
        int hh = h + 1 - r;                 // adjoint: row h reads conv-out row h+1-kh
        if ((unsigned)hh >= 32u) continue;  // block-uniform

        __syncthreads();                    // previous row's readers done

        // ---- stage row r: sites wv, wv+4, wv+8 ----
        for (int s = wv; s < 10; s += 4) {
            int ww = w0 - 1 + s;
            if ((unsigned)ww >= 32u) {
                short8 z = (short8)0;
                #pragma unroll
                for (int j = 0; j < 4; j++) {
                    int chunk = 2 * j + ch;
                    *(short8*)&tiles[s][o * 64 + ((chunk ^ (o & 7)) << 3)] = z;
                }
                continue;
            }
            const float* base = src + ((size_t)b * 65536 + (size_t)(hh * 32 + ww) * 64) * 32;
            bool ctr = (r == 1) && (s >= 1) && (s <= 8);   // center row: each elem staged once
            #pragma unroll
            for (int j = 0; j < 4; j++) {
                int co0 = j * 16 + ch * 8;
                float g[8];
                #pragma unroll
                for (int e = 0; e < 8; e++) g[e] = base[(co0 + e) * 32 + o];
                if (ctr) {
                    float4 bv0 = *(const float4*)(bias + co0);
                    float4 bv1 = *(const float4*)(bias + co0 + 4);
                    bp = fmaf(g[0], bv0.x, bp); bp = fmaf(g[1], bv0.y, bp);
                    bp = fmaf(g[2], bv0.z, bp); bp = fmaf(g[3], bv0.w, bp);
                    bp = fmaf(g[4], bv1.x, bp); bp = fmaf(g[5], bv1.y, bp);
                    bp = fmaf(g[6], bv1.z, bp); bp = fmaf(g[7], bv1.w, bp);
                }
                short8 v;
                #pragma unroll
                for (int e = 0; e < 8; e++) v[e] = (short)f2bf(g[e]);
                int chunk = 2 * j + ch;
                *(short8*)&tiles[s][o * 64 + ((chunk ^ (o & 7)) << 3)] = v;
            }
        }

        __syncthreads();                    // row staged

        // ---- compute row r (kidx outer: only 6 A-frags live) ----
        #pragma unroll
        for (int kidx = 0; kidx < 4; kidx++) {
            short8 A[3][2];
            #pragma unroll
            for (int kw = 0; kw < 3; kw++)
                #pragma unroll
                for (int c = 0; c < 2; c++)
                    A[kw][c] = *(const short8*)&ktb[(((r * 3 + kw) * 64) + c * 32 + (l & 31)) * 64
                                                    + kidx * 16 + ch * 8];
            #pragma unroll
            for (int si = 0; si < 4; si++) {
                int s = 2 * wv + si;
                int chunk = kidx * 2 + ch;
                short8 Bf = *(const short8*)&tiles[s][o * 64 + ((chunk ^ (o & 7)) << 3)];
                #pragma unroll
                for (int tw = 0; tw < 2; tw++) {
                    int kw = tw + 2 - si;              // compile-time under unroll
                    if (kw >= 0 && kw <= 2) {
                        #pragma unroll
                        for (int c = 0; c < 2; c++)
                            acc[tw][c] = __builtin_amdgcn_mfma_f32_32x32x16_bf16(
                                A[kw][c], Bf, acc[tw][c], 0, 0, 0);
                    }
                }
            }
        }
    }

    // ---- bias reduction: alias tiles as scratch (all compute done) ----
    __syncthreads();
    float* bsum = (float*)&tiles[0][0];
    if (t < 32) bsum[t] = 0.f;
    __syncthreads();
    atomicAdd(&bsum[o], bp);
    __syncthreads();
    if (t < 32) atomicAdd(&bdst[b * 32 + t], bsum[t]);

    // ---- stores: col = o (coalesced), row = (reg&3)+8*(reg>>2)+4*(lane>>5) ----
    int wa = w0 + 2 * wv;
    #pragma unroll
    for (int tw = 0; tw < 2; tw++) {
        int w = wa + tw;
        #pragma unroll
        for (int c = 0; c < 2; c++) {
            float* base = dst + ((size_t)b * 65536 + (size_t)(h * 32 + w) * 64 + c * 32) * 32;
            #pragma unroll
            for (int reg = 0; reg < 16; reg++) {
                int row = (reg & 3) + 8 * (reg >> 2) + 4 * (l >> 5);
                base[row * 32 + o] = acc[tw][c][reg];
            }
        }
    }
}

extern "C" void kernel_launch(void* const* d_in, const int* in_sizes, int n_in,
                              void* d_out, int out_size, void* d_ws, size_t ws_size,
                              hipStream_t stream) {
    const float* wu   = (const float*)d_in[1];
    const float* buI  = (const float*)d_in[2];
    const float* wl   = (const float*)d_in[3];
    const float* blI  = (const float*)d_in[4];
    const float* kk   = (const float*)d_in[5];
    const float* bias = (const float*)d_in[6];

    float* out  = (float*)d_out;
    float* outU = out;
    float* buO  = out + 16777216;
    float* outL = out + 16777216 + 256;
    float* blO  = out + 2 * 16777216 + 256;

    uint16_t* ktb = (uint16_t*)d_ws;   // 73728 B

    k_prep<<<146, 256, 0, stream>>>(kk, ktb, buI, blI, buO, blO);
    k_main<<<2048, 256, 0, stream>>>(wu, wl, ktb, bias, outU, outL, buO, blO);
}